// Round 1
// baseline (933.360 us; speedup 1.0000x reference)
//
#include <hip/hip_runtime.h>
#include <hip/hip_bf16.h>
#include <stdint.h>

// ---------- types ----------
typedef short  bf16x8 __attribute__((ext_vector_type(8)));   // 8 bf16 (4 VGPRs)
typedef short  bf16x4 __attribute__((ext_vector_type(4)));
typedef float  f32x4  __attribute__((ext_vector_type(4)));

static __device__ __forceinline__ short f2bf(float f) {
    uint32_t u = __builtin_bit_cast(uint32_t, f);
    u = u + 0x7fffu + ((u >> 16) & 1u);          // RNE
    return (short)(u >> 16);
}

// ---------------------------------------------------------------
// gather + transpose + fp32->bf16:
//   out[d][k] = src[ row(k) ][ d ],  d in [0,128), k in [0,K)
//   row(k) = chain2 ? chain2[chain1[k]] : (chain1 ? chain1[k] : k)
// grid = K/64 blocks, 256 threads
// ---------------------------------------------------------------
__global__ __launch_bounds__(256) void k_gatherT(
    const float* __restrict__ src, const int* __restrict__ chain1,
    const int* __restrict__ chain2, short* __restrict__ out, int K) {
    __shared__ float tile[64][130];              // pitch 130: 2-way read conflict (free)
    const int k0 = blockIdx.x * 64;
    const int t  = threadIdx.x;

    #pragma unroll
    for (int p = 0; p < 8; ++p) {
        int i  = p * 256 + t;                    // 0..2047
        int r  = i >> 5;                         // 0..63
        int f4 = i & 31;                         // 0..31 (float4 within row)
        int row = k0 + r;
        if (chain1) row = chain1[row];
        if (chain2) row = chain2[row];
        float4 v = *reinterpret_cast<const float4*>(src + (size_t)row * 128 + f4 * 4);
        *reinterpret_cast<float2*>(&tile[r][f4 * 4 + 0]) = make_float2(v.x, v.y);
        *reinterpret_cast<float2*>(&tile[r][f4 * 4 + 2]) = make_float2(v.z, v.w);
    }
    __syncthreads();

    const int kl = t & 63;
    const int d0 = (t >> 6) * 32;
    #pragma unroll
    for (int j = 0; j < 32; ++j) {
        int d = d0 + j;
        out[(size_t)d * K + k0 + kl] = f2bf(tile[kl][d]);
    }
}

// ---------------------------------------------------------------
// split-K GEMM:  C[m][n] += sum_k A[m][k] * BT[n][k]
//   A  : fp32 [M][Ktot] row-major
//   BT : bf16 [128][Ktot] (n-major, k contiguous)
//   C  : fp32 [M][128], accumulated with atomicAdd (pre-zeroed)
// block = 256 thr (4 waves), BM=128, N=128, BK=32
// grid  = (M/128) * nSplits,  kChunk * nSplits == Ktot, kChunk % 32 == 0
// ---------------------------------------------------------------
#define BM  128
#define BK  32
#define PAD 8

__global__ __launch_bounds__(256) void k_gemm_splitk(
    const float* __restrict__ A, const short* __restrict__ BT,
    float* __restrict__ C, int M, int Ktot, int kChunk) {
    __shared__ short As[BM][BK + PAD];
    __shared__ short Bs[128][BK + PAD];

    const int mtiles = M / BM;
    const int mtile  = blockIdx.x % mtiles;
    const int split  = blockIdx.x / mtiles;
    const int m0     = mtile * BM;
    const int kstart = split * kChunk;
    const int kend   = kstart + kChunk;

    const int t    = threadIdx.x;
    const int wave = t >> 6;
    const int lane = t & 63;
    const int rl   = lane & 15;
    const int hk   = (lane >> 4) * 8;

    f32x4 acc[2][8];
    #pragma unroll
    for (int i = 0; i < 2; ++i)
        #pragma unroll
        for (int j = 0; j < 8; ++j)
            acc[i][j] = (f32x4){0.f, 0.f, 0.f, 0.f};

    for (int k0 = kstart; k0 < kend; k0 += BK) {
        // ---- stage A tile: 128 rows x 32 cols, fp32 -> bf16
        {
            const int f4    = t & 7;
            const int rbase = t >> 3;
            #pragma unroll
            for (int p = 0; p < 4; ++p) {
                int r = rbase + p * 32;
                float4 v = *reinterpret_cast<const float4*>(
                    A + (size_t)(m0 + r) * Ktot + k0 + f4 * 4);
                bf16x4 s; s[0]=f2bf(v.x); s[1]=f2bf(v.y); s[2]=f2bf(v.z); s[3]=f2bf(v.w);
                *reinterpret_cast<bf16x4*>(&As[r][f4 * 4]) = s;
            }
        }
        // ---- stage B tile: 128 d-rows x 32 k (bf16, already converted)
        {
            const int c8    = t & 3;
            const int dbase = t >> 2;
            #pragma unroll
            for (int p = 0; p < 2; ++p) {
                int d = dbase + p * 64;
                bf16x8 v = *reinterpret_cast<const bf16x8*>(
                    BT + (size_t)d * Ktot + k0 + c8 * 8);
                *reinterpret_cast<bf16x8*>(&Bs[d][c8 * 8]) = v;
            }
        }
        __syncthreads();

        bf16x8 a0 = *reinterpret_cast<const bf16x8*>(&As[wave * 32 +      rl][hk]);
        bf16x8 a1 = *reinterpret_cast<const bf16x8*>(&As[wave * 32 + 16 + rl][hk]);
        #pragma unroll
        for (int fn = 0; fn < 8; ++fn) {
            bf16x8 b = *reinterpret_cast<const bf16x8*>(&Bs[fn * 16 + rl][hk]);
            acc[0][fn] = __builtin_amdgcn_mfma_f32_16x16x32_bf16(a0, b, acc[0][fn], 0, 0, 0);
            acc[1][fn] = __builtin_amdgcn_mfma_f32_16x16x32_bf16(a1, b, acc[1][fn], 0, 0, 0);
        }
        __syncthreads();
    }

    const int rg = (lane >> 4) * 4;
    #pragma unroll
    for (int fm = 0; fm < 2; ++fm)
        #pragma unroll
        for (int fn = 0; fn < 8; ++fn)
            #pragma unroll
            for (int j = 0; j < 4; ++j) {
                int row = m0 + wave * 32 + fm * 16 + rg + j;
                int col = fn * 16 + rl;
                atomicAdd(&C[(size_t)row * 128 + col], acc[fm][fn][j]);
            }
}

// ---------------------------------------------------------------
// projection:  out[m][j] = act( sum_{k<128} agg[m][k]*wT[j][k]
//                             + sum_{k<128} gsrc[row(m)][k]*wT[j][128+k] )
//   row(m) = chain2 ? chain2[chain1[m]] : chain1[m]
//   wT : bf16 [128][256]
// grid = M/128 blocks, 256 threads
// ---------------------------------------------------------------
__global__ __launch_bounds__(256) void k_proj(
    const float* __restrict__ agg, const float* __restrict__ gsrc,
    const int* __restrict__ chain1, const int* __restrict__ chain2,
    const short* __restrict__ wT, float* __restrict__ outp,
    int M, int relu) {
    __shared__ short As[BM][BK + PAD];
    __shared__ short Ws[128][BK + PAD];

    const int m0   = blockIdx.x * BM;
    const int t    = threadIdx.x;
    const int wave = t >> 6;
    const int lane = t & 63;
    const int rl   = lane & 15;
    const int hk   = (lane >> 4) * 8;

    f32x4 acc[2][8];
    #pragma unroll
    for (int i = 0; i < 2; ++i)
        #pragma unroll
        for (int j = 0; j < 8; ++j)
            acc[i][j] = (f32x4){0.f, 0.f, 0.f, 0.f};

    for (int k0 = 0; k0 < 256; k0 += BK) {
        {
            const int f4    = t & 7;
            const int rbase = t >> 3;
            #pragma unroll
            for (int p = 0; p < 4; ++p) {
                int r = rbase + p * 32;
                int m = m0 + r;
                float4 v;
                if (k0 < 128) {
                    v = *reinterpret_cast<const float4*>(agg + (size_t)m * 128 + k0 + f4 * 4);
                } else {
                    int row = chain1[m];
                    if (chain2) row = chain2[row];
                    v = *reinterpret_cast<const float4*>(gsrc + (size_t)row * 128 + (k0 - 128) + f4 * 4);
                }
                bf16x4 s; s[0]=f2bf(v.x); s[1]=f2bf(v.y); s[2]=f2bf(v.z); s[3]=f2bf(v.w);
                *reinterpret_cast<bf16x4*>(&As[r][f4 * 4]) = s;
            }
        }
        {
            const int c8    = t & 3;
            const int dbase = t >> 2;
            #pragma unroll
            for (int p = 0; p < 2; ++p) {
                int d = dbase + p * 64;
                bf16x8 v = *reinterpret_cast<const bf16x8*>(wT + (size_t)d * 256 + k0 + c8 * 8);
                *reinterpret_cast<bf16x8*>(&Ws[d][c8 * 8]) = v;
            }
        }
        __syncthreads();

        bf16x8 a0 = *reinterpret_cast<const bf16x8*>(&As[wave * 32 +      rl][hk]);
        bf16x8 a1 = *reinterpret_cast<const bf16x8*>(&As[wave * 32 + 16 + rl][hk]);
        #pragma unroll
        for (int fn = 0; fn < 8; ++fn) {
            bf16x8 b = *reinterpret_cast<const bf16x8*>(&Ws[fn * 16 + rl][hk]);
            acc[0][fn] = __builtin_amdgcn_mfma_f32_16x16x32_bf16(a0, b, acc[0][fn], 0, 0, 0);
            acc[1][fn] = __builtin_amdgcn_mfma_f32_16x16x32_bf16(a1, b, acc[1][fn], 0, 0, 0);
        }
        __syncthreads();
    }

    const int rg = (lane >> 4) * 4;
    #pragma unroll
    for (int fm = 0; fm < 2; ++fm)
        #pragma unroll
        for (int fn = 0; fn < 8; ++fn)
            #pragma unroll
            for (int j = 0; j < 4; ++j) {
                int row = m0 + wave * 32 + fm * 16 + rg + j;
                int col = fn * 16 + rl;
                float v = acc[fm][fn][j];
                if (relu) v = v > 0.f ? v : 0.f;
                outp[(size_t)row * 128 + col] = v;
            }
}

// ---------------------------------------------------------------
extern "C" void kernel_launch(void* const* d_in, const int* in_sizes, int n_in,
                              void* d_out, int out_size, void* d_ws, size_t ws_size,
                              hipStream_t stream) {
    const float* features   = (const float*)d_in[0];   // [100000][128]
    const int*   src_nodes  = (const int*)  d_in[1];   // [25600]
    const int*   neighbors1 = (const int*)  d_in[2];   // [5120]
    const int*   nodes1     = (const int*)  d_in[3];   // [25600]
    const float* adj1       = (const float*)d_in[4];   // [5120][25600]
    const int*   neighbors2 = (const int*)  d_in[5];   // [512]
    const int*   nodes2     = (const int*)  d_in[6];   // [5120]
    const float* adj2       = (const float*)d_in[7];   // [512][5120]
    const float* w1         = (const float*)d_in[8];   // [256][128]
    const float* w2         = (const float*)d_in[9];   // [256][128]

    char* ws = (char*)d_ws;
    short* xgT1 = (short*)(ws + 0);           // bf16 [128][25600]  6,553,600 B
    float* agg1 = (float*)(ws + 6553600);     // f32  [5120][128]   2,621,440 B
    float* x1   = (float*)(ws + 9175040);     // f32  [5120][128]   2,621,440 B
    short* x1gT = (short*)(ws + 11796480);    // bf16 [128][5120]   1,310,720 B
    float* agg2 = (float*)(ws + 13107200);    // f32  [512][128]      262,144 B
    short* w1T  = (short*)(ws + 13369344);    // bf16 [128][256]       65,536 B
    short* w2T  = (short*)(ws + 13434880);    // bf16 [128][256]       65,536 B

    hipMemsetAsync(agg1, 0, (size_t)5120 * 128 * 4, stream);
    hipMemsetAsync(agg2, 0, (size_t)512  * 128 * 4, stream);

    // layer-1 B operand: xgT1[d][k] = features[src_nodes[nodes1[k]]][d]
    k_gatherT<<<400, 256, 0, stream>>>(features, nodes1, src_nodes, xgT1, 25600);
    // weight transposes (identity chain)
    k_gatherT<<<4, 256, 0, stream>>>(w1, nullptr, nullptr, w1T, 256);
    k_gatherT<<<4, 256, 0, stream>>>(w2, nullptr, nullptr, w2T, 256);

    // layer-1 GEMM: agg1 += adj1 @ xgT1^T   (40 mtiles x 32 splits, kChunk=800)
    k_gemm_splitk<<<1280, 256, 0, stream>>>(adj1, xgT1, agg1, 5120, 25600, 800);

    // x1 = relu([agg1 | features[src_nodes[neighbors1]]] @ w1)
    k_proj<<<40, 256, 0, stream>>>(agg1, features, neighbors1, src_nodes, w1T, x1, 5120, 1);

    // layer-2 B operand: x1gT[d][k] = x1[nodes2[k]][d]
    k_gatherT<<<80, 256, 0, stream>>>(x1, nodes2, nullptr, x1gT, 5120);

    // layer-2 GEMM: agg2 += adj2 @ x1gT^T   (4 mtiles x 32 splits, kChunk=160)
    k_gemm_splitk<<<128, 256, 0, stream>>>(adj2, x1gT, agg2, 512, 5120, 160);

    // out = [agg2 | x1[neighbors2]] @ w2
    k_proj<<<4, 256, 0, stream>>>(agg2, x1, neighbors2, nullptr, w2T, (float*)d_out, 512, 0);
}